// Round 9
// baseline (499.730 us; speedup 1.0000x reference)
//
#include <hip/hip_runtime.h>
#include <hip/hip_bf16.h>

// Grouped conv2d as implicit GEMM per group:
//   out[b*64+co][h][w] = sum_{ci,kh,kw} W[b*64+co][ci][kh][kw] * x[b*64+ci][h+kh-1][w+kw-1]
// bf16 MFMA (16x16x32), fp32 accumulate.
//
// R9 changes vs R8 (null: af L2 traffic is per-wave -> invariant to TILE_H;
// 9.4 MB/CU af re-reads + per-tap L2 latency is the unaddressed term):
//  - af broadcast through LDS: each kc-stage also copies the 36.9KB af set
//    (9 taps x 4 mt x 1KB, bf16, plain 16B-chunk copy) into a second LDS
//    buffer; compute reads af via lane-linear ds_read_b128 (0-conflict).
//    Per-CU af L2 traffic /8; af latency L2(~300cy) -> LDS(~120cy).
//  - xs XCOLS 68->66 (bank-safe: all accesses live in 64B column-blocks).
//    LDS total 42.2+36.9 = 79.1KB -> 2 blocks/CU (same residency as R8).
//  - kc phase order staggered by block parity (decorrelate HBM bursts).
//  - __launch_bounds__(512,4): VGPR<=128 so 2 full blocks always fit.

typedef __bf16 bf16x8 __attribute__((ext_vector_type(8)));
typedef float  f32x4  __attribute__((ext_vector_type(4)));

#define NB 32
#define NH 256
#define NW 256
#define TILE_H 8
#define TILE_W 64
#define XROWS 10    // TILE_H + 2 (halo)
#define XCOLS 66    // TILE_W + 2
#define HWSZ ((size_t)NH * NW)

// ---------------------------------------------------------------------------
// Repack weights into MFMA A-fragment order:
//   pk[((b*9+tap)*4+mt)*2+kc][lane][j]  (bf16, 16B per lane)
// value = W[b*64 + mt*16 + (lane&15)][kc*32 + (lane>>4)*8 + j][tap]
// ---------------------------------------------------------------------------
__global__ void repack_weights_kernel(const float* __restrict__ wsrc,
                                      __bf16* __restrict__ pk) {
    int t = blockIdx.x * blockDim.x + threadIdx.x;
    if (t >= NB * 9 * 4 * 2 * 64) return;
    int lane = t & 63;
    int r = t >> 6;
    int kc = r & 1;  r >>= 1;
    int mt = r & 3;  r >>= 2;
    int tap = r % 9;
    int b   = r / 9;
    int co  = b * 64 + mt * 16 + (lane & 15);
    int ci0 = kc * 32 + (lane >> 4) * 8;
    bf16x8 v;
#pragma unroll
    for (int j = 0; j < 8; ++j) {
        v[j] = (__bf16)wsrc[(co * 64 + ci0 + j) * 9 + tap];
    }
    *reinterpret_cast<bf16x8*>(pk + (size_t)t * 8) = v;
}

// ---------------------------------------------------------------------------
// Main conv kernel. Block = (group b, 8 output rows, 64 output cols), 8 waves.
// Wave wid owns output row h0+wid (all 64 co).
// LDS xs: one 32-ci half-tile [r][c][32], octet o of col c at 8*(o^((c>>1)&3)).
// LDS afs: 36 fragments x 512 bf16 (lane-linear), staged per kc phase.
// ---------------------------------------------------------------------------
__launch_bounds__(512, 4)
__global__ void conv_mfma_kernel(const float* __restrict__ x,
                                 const __bf16* __restrict__ pk,
                                 float* __restrict__ out) {
    __shared__ __align__(16) __bf16 xs[XROWS * XCOLS * 32];   // 42240 B
    __shared__ __align__(16) __bf16 afs[36 * 512];            // 36864 B

    // XCD-aware bijective swizzle: 4096 blocks, 8 XCDs -> 512-chunk per XCD
    const int orig = blockIdx.x;
    const int wg   = (orig & 7) * 512 + (orig >> 3);
    const int b    = wg >> 7;            // 0..31
    const int by   = (wg >> 2) & 31;     // 0..31
    const int bx   = wg & 3;             // 0..3
    const int h0   = by * TILE_H;
    const int w0   = bx * TILE_W;

    const int tid  = threadIdx.x;
    const int wid  = tid >> 6;           // 0..7
    const int lane = tid & 63;
    const int nl   = lane & 15;
    const int kgrp = lane >> 4;          // 0..3

    const __bf16* pkb = pk + (size_t)b * 36864;

    f32x4 acc[4][4];   // [mt][q]
#pragma unroll
    for (int mt = 0; mt < 4; ++mt)
#pragma unroll
        for (int q = 0; q < 4; ++q)
            acc[mt][q] = (f32x4){0.f, 0.f, 0.f, 0.f};

    // staging thread constants: thread = (column c = lane, oct = wid&3,
    // row-half = wid>>2 -> rows rbase..rbase+4)
    const int c     = lane;              // 0..63 -> w = w0-1+c
    const int w     = w0 - 1 + c;
    const int wcl   = min(max(w, 0), NW - 1);
    const bool wbad = (w != wcl);
    const int oct   = wid & 3;
    const int rbase = (wid >> 2) * 5;    // 0 or 5
    const int sciw  = ((oct ^ ((c >> 1) & 3)) * 8);   // swizzled octet offset

    // halo thread constants (threads 0..79: c=64,65; 10 rows x 2 sides x 4 oct)
    const int hr    = tid >> 3;              // 0..9
    const int hside = (tid >> 2) & 1;        // 0,1 -> c = 64,65
    const int hoct  = tid & 3;               // local ci octet
    const int hch   = 64 + hside;
    const int hw    = w0 + 63 + hside;
    const int hwc   = min(hw, NW - 1);

    // ---- stage phase kcv: af broadcast copy + 32-ci x tile ----
    auto stage = [&](int kcv) {
        // af: 2304 16B-chunks -> afs (bf16 copy, coalesced; frag/wave/iter)
#pragma unroll
        for (int i = 0; i < 5; ++i) {
            const int idx = tid + i * 512;
            if (i < 4 || tid < 256) {            // idx < 2304
                const int f = idx >> 6;          // fragment 0..35 (tap*4+mt)
                const int wo = idx & 63;
                bf16x8 v = *reinterpret_cast<const bf16x8*>(
                    pkb + ((size_t)(f * 2 + kcv) * 512 + wo * 8));
                *reinterpret_cast<bf16x8*>(afs + f * 512 + wo * 8) = v;
            }
        }

        // x tile: coalesced scalar loads, b128 swizzled writes
        const int cibase = b * 64 + kcv * 32 + oct * 8;
        const float* colp = x + (size_t)cibase * HWSZ + wcl;

        float hv[8];
        if (tid < 80) {
            const int h  = h0 - 1 + hr;
            const int hc = min(max(h, 0), NH - 1);
            const float* src = x + ((size_t)(b * 64 + kcv * 32 + hoct * 8) * NH + hc) * NW + hwc;
#pragma unroll
            for (int j = 0; j < 8; ++j) hv[j] = src[j * HWSZ];
            if (h != hc || hw != hwc) {
#pragma unroll
                for (int j = 0; j < 8; ++j) hv[j] = 0.f;
            }
        }

        float va[8], vb[8], vc[8];
        auto load8 = [&](int r, float* v) {   // r = local row 0..4
            const int h  = h0 - 1 + rbase + r;
            const int hc = min(max(h, 0), NH - 1);
            const float* src = colp + (size_t)hc * NW;
#pragma unroll
            for (int j = 0; j < 8; ++j) v[j] = src[j * HWSZ];
            if (wbad || h != hc) {
#pragma unroll
                for (int j = 0; j < 8; ++j) v[j] = 0.f;
            }
        };
        auto store8 = [&](int r, const float* v) {
            const int rr = rbase + r;
            bf16x8 o;
#pragma unroll
            for (int j = 0; j < 8; ++j) o[j] = (__bf16)v[j];
            *reinterpret_cast<bf16x8*>(xs + (rr * XCOLS + c) * 32 + sciw) = o;
        };

        // triple ping-pong: 3 load8s in flight -> 2 serialized HBM rounds
        load8(0, va);
        load8(1, vb);
        load8(2, vc);
        store8(0, va); load8(3, va);
        store8(1, vb); load8(4, vb);
        store8(2, vc);
        store8(3, va);
        store8(4, vb);

        if (tid < 80) {
            bf16x8 o;
#pragma unroll
            for (int j = 0; j < 8; ++j) o[j] = (__bf16)hv[j];
            // slot(64)=slot(65)=0 -> octet position = hoct
            *reinterpret_cast<bf16x8*>(xs + (hr * XCOLS + hch) * 32 + hoct * 8) = o;
        }
    };

    // ---- compute one kc phase: 9 taps; af from LDS (lane-linear) ----
    auto compute = [&]() {
#pragma unroll
        for (int tap = 0; tap < 9; ++tap) {
            bf16x8 afr[4];
#pragma unroll
            for (int mt = 0; mt < 4; ++mt)
                afr[mt] = *reinterpret_cast<const bf16x8*>(
                    afs + (tap * 4 + mt) * 512 + lane * 8);
            const int kh = tap / 3;
            const int kw = tap - kh * 3;
            const int rowbase = (wid + kh) * XCOLS;
#pragma unroll
            for (int q = 0; q < 4; ++q) {
                const int cc   = q * 16 + nl + kw;          // 0..65
                const int slot = (cc >> 1) & 3;
                bf16x8 bfv = *reinterpret_cast<const bf16x8*>(
                    xs + (rowbase + cc) * 32 + ((kgrp ^ slot) * 8));
#pragma unroll
                for (int mt = 0; mt < 4; ++mt)
                    acc[mt][q] = __builtin_amdgcn_mfma_f32_16x16x32_bf16(
                        afr[mt], bfv, acc[mt][q], 0, 0, 0);
            }
        }
    };

    // ---- phase driver: kc order staggered by block parity ----
    const int par = wg & 1;
    stage(par);
    __syncthreads();
    compute();
    __syncthreads();          // protect xs/afs before overwrite
    stage(par ^ 1);
    __syncthreads();
    compute();

    // ---- epilogue: D lane layout col=lane&15, row=(lane>>4)*4+reg ----
    const int mrow = kgrp * 4;
    const int h = h0 + wid;
#pragma unroll
    for (int mt = 0; mt < 4; ++mt) {
#pragma unroll
        for (int q = 0; q < 4; ++q) {
            const int ww = w0 + q * 16 + nl;
#pragma unroll
            for (int rg = 0; rg < 4; ++rg) {
                const int co = mt * 16 + mrow + rg;
                out[((size_t)(b * 64 + co) * NH + h) * NW + ww] = acc[mt][q][rg];
            }
        }
    }
}

extern "C" void kernel_launch(void* const* d_in, const int* in_sizes, int n_in,
                              void* d_out, int out_size, void* d_ws, size_t ws_size,
                              hipStream_t stream) {
    const float* x = (const float*)d_in[0];     // [1, 32*64, 256, 256] fp32
    const float* w = (const float*)d_in[1];     // [2048, 64, 3, 3] fp32
    float* out = (float*)d_out;                 // [1, 2048, 256, 256] fp32
    __bf16* pk = (__bf16*)d_ws;                 // 2.25 MB repacked bf16 weights

    {
        int total = NB * 9 * 4 * 2 * 64;        // 147456
        int blk = 256;
        int grid = (total + blk - 1) / blk;     // 576
        hipLaunchKernelGGL(repack_weights_kernel, dim3(grid), dim3(blk), 0, stream,
                           w, pk);
    }
    {
        dim3 grid(4096);                        // 1D, swizzled in-kernel
        hipLaunchKernelGGL(conv_mfma_kernel, grid, dim3(512), 0, stream,
                           x, pk, out);
    }
}

// Round 10
// 323.813 us; speedup vs baseline: 1.5433x; 1.5433x over previous
//
#include <hip/hip_runtime.h>
#include <hip/hip_bf16.h>

// Grouped conv2d as implicit GEMM per group:
//   out[b*64+co][h][w] = sum_{ci,kh,kw} W[b*64+co][ci][kh][kw] * x[b*64+ci][h+kh-1][w+kw-1]
// bf16 MFMA (16x16x32), fp32 accumulate.
//
// R10 changes vs R7 (348us; staging = 2-3 serialized HBM latency rounds in
// registers; R5/R6/R9 all proved register-staging spills):
//  - bulk staging via global_load_lds (zero VGPRs): 12 dwordx4 instrs/wave
//    fill scratch[6][32ci][64w] fp32 (linear dest, 16B-contiguous source).
//    One vmcnt(0) drain at the barrier (1 exposed HBM round vs 2-3).
//  - LDS->LDS cvt pass: 48 ds_read_b32 (2-way banks, free) + cvt + 6
//    ds_write_b128 into the EXACT R7 xs layout (verified 0-conflict).
//    All bounds zeroing via register predicates (no OOB global addrs:
//    gload covers w0..w0+63 only; halo cols via tiny 48-thread reg path).
//  - kc=1 gloads issued between taps 3-4 of compute(kc0) (after that
//    window's af loads -> in-order vmcnt doesn't stall early taps).
//  - compute/epilogue/af-ring byte-identical to R7.

typedef __bf16 bf16x8 __attribute__((ext_vector_type(8)));
typedef float  f32x4  __attribute__((ext_vector_type(4)));

#define NB 32
#define NH 256
#define NW 256
#define TILE_H 4
#define TILE_W 64
#define XROWS 6     // TILE_H + 2 (halo)
#define XCOLS 68    // TILE_W + 2, padded
#define HWSZ ((size_t)NH * NW)

template<int P> struct IC { static constexpr int v = P; };

__device__ __forceinline__ void gload16(const float* g, float* lds) {
    __builtin_amdgcn_global_load_lds(
        (const __attribute__((address_space(1))) unsigned int*)g,
        (__attribute__((address_space(3))) unsigned int*)lds, 16, 0, 0);
}

// ---------------------------------------------------------------------------
// Repack weights into MFMA A-fragment order:
//   pk[((b*9+tap)*4+mt)*2+kc][lane][j]  (bf16, 16B per lane)
// value = W[b*64 + mt*16 + (lane&15)][kc*32 + (lane>>4)*8 + j][tap]
// ---------------------------------------------------------------------------
__global__ void repack_weights_kernel(const float* __restrict__ wsrc,
                                      __bf16* __restrict__ pk) {
    int t = blockIdx.x * blockDim.x + threadIdx.x;
    if (t >= NB * 9 * 4 * 2 * 64) return;
    int lane = t & 63;
    int r = t >> 6;
    int kc = r & 1;  r >>= 1;
    int mt = r & 3;  r >>= 2;
    int tap = r % 9;
    int b   = r / 9;
    int co  = b * 64 + mt * 16 + (lane & 15);
    int ci0 = kc * 32 + (lane >> 4) * 8;
    bf16x8 v;
#pragma unroll
    for (int j = 0; j < 8; ++j) {
        v[j] = (__bf16)wsrc[(co * 64 + ci0 + j) * 9 + tap];
    }
    *reinterpret_cast<bf16x8*>(pk + (size_t)t * 8) = v;
}

// ---------------------------------------------------------------------------
// Main conv kernel. Block = (group b, 4 output rows, 64 output cols), 4 waves.
// scratch: [6][32 ci][64 w] fp32, filled by global_load_lds (linear).
// xs: [r][c][32] bf16, octet o of column c at 8*(o ^ ((c>>1)&3)) (R7 layout).
// Phases kc=0,1 reuse both buffers.
// ---------------------------------------------------------------------------
__launch_bounds__(256)
__global__ void conv_mfma_kernel(const float* __restrict__ x,
                                 const __bf16* __restrict__ pk,
                                 float* __restrict__ out) {
    __shared__ __align__(16) __bf16 xs[XROWS * XCOLS * 32];   // 26112 B
    __shared__ __align__(16) float  scratch[XROWS * 32 * 64]; // 49152 B

    // XCD-aware bijective swizzle: 8192 blocks, 8 XCDs
    const int orig = blockIdx.x;
    const int wg   = (orig & 7) * 1024 + (orig >> 3);
    const int b    = wg >> 8;            // 0..31
    const int by   = (wg >> 2) & 63;     // 0..63
    const int bx   = wg & 3;             // 0..3
    const int h0   = by * TILE_H;
    const int w0   = bx * TILE_W;

    const int tid  = threadIdx.x;
    const int wid  = tid >> 6;
    const int lane = tid & 63;
    const int nl   = lane & 15;
    const int kgrp = lane >> 4;          // 0..3

    const __bf16* pkb = pk + (size_t)b * 9 * 4096;

    // A-fragment 4-slot ring over g = kc*9+tap (all indices compile-time).
    bf16x8 af[4][4];
    auto load_af = [&](int g) {           // g in [0,18)
        const int tap = (g >= 9) ? g - 9 : g;
        const int kc  = (g >= 9) ? 1 : 0;
        const int sl  = g & 3;
#pragma unroll
        for (int mt = 0; mt < 4; ++mt)
            af[sl][mt] = *reinterpret_cast<const bf16x8*>(
                pkb + tap * 4096 + ((mt * 2 + kc) * 64 + lane) * 8);
    };

    f32x4 acc[4][4];   // [mt][q]
#pragma unroll
    for (int mt = 0; mt < 4; ++mt)
#pragma unroll
        for (int q = 0; q < 4; ++q)
            acc[mt][q] = (f32x4){0.f, 0.f, 0.f, 0.f};

    // halo thread constants (threads 0..47: columns c=0 and c=65)
    const int hside = tid & 1;               // 0 -> c=0 (w0-1), 1 -> c=65 (w0+64)
    const int hidx  = tid >> 1;              // 0..23
    const int hrr   = hidx % 6;
    const int hoo   = hidx / 6;              // ci octet 0..3
    const int hch   = hside ? 65 : 0;
    const int hwv   = hside ? (w0 + 64) : (w0 - 1);
    float hreg[8];
    bool  hz = false;

    // ---- issue bulk gloads for phase kcv (fire-and-forget, 12/wave) ----
    auto issue_gload = [&](int kcv) {
#pragma unroll
        for (int m = 0; m < 12; ++m) {
            const int I  = wid * 12 + m;     // 0..47
            const int r  = I >> 3;           // 0..5
            const int cb = I & 7;            // 4-ci block
            const int hh = h0 - 1 + r;
            const int hc = min(max(hh, 0), NH - 1);
            const float* src = x
                + ((size_t)(b * 64 + kcv * 32 + cb * 4 + (lane >> 4)) * NH + hc) * NW
                + w0 + (lane & 15) * 4;
            gload16(src, scratch + (r * 32 + cb * 4) * 64);
        }
    };

    // ---- issue halo loads for phase kcv (threads 0..47, 8 floats each) ----
    auto issue_halo = [&](int kcv) {
        if (tid < 48) {
            const int hh = h0 - 1 + hrr;
            hz = (hwv < 0) || (hwv > NW - 1) || (hh < 0) || (hh > NH - 1);
            const int wc2 = min(max(hwv, 0), NW - 1);
            const int hc2 = min(max(hh, 0), NH - 1);
            const float* s = x + ((size_t)(b * 64 + kcv * 32 + hoo * 8) * NH + hc2) * NW + wc2;
#pragma unroll
            for (int j = 0; j < 8; ++j) hreg[j] = s[j * HWSZ];
        }
    };

    // ---- cvt pass: scratch(fp32) -> xs(bf16, R7 swizzled layout) ----
    auto cvt = [&]() {
#pragma unroll
        for (int rr = 0; rr < XROWS; ++rr) {
            const int hh = h0 - 1 + rr;
            const bool z = (hh < 0) || (hh > NH - 1);
            float v[8];
#pragma unroll
            for (int j = 0; j < 8; ++j)
                v[j] = scratch[(rr * 32 + wid * 8 + j) * 64 + lane];
            bf16x8 o8;
#pragma unroll
            for (int j = 0; j < 8; ++j) o8[j] = z ? (__bf16)0.f : (__bf16)v[j];
            const int c = lane + 1;          // scratch pos lane -> xs col lane+1
            *reinterpret_cast<bf16x8*>(
                xs + (rr * XCOLS + c) * 32 + ((wid ^ ((c >> 1) & 3)) * 8)) = o8;
        }
        if (tid < 48) {
            bf16x8 o8;
#pragma unroll
            for (int j = 0; j < 8; ++j) o8[j] = hz ? (__bf16)0.f : (__bf16)hreg[j];
            // slot(0)=slot(65)=0 -> octet position = hoo
            *reinterpret_cast<bf16x8*>(xs + (hrr * XCOLS + hch) * 32 + hoo * 8) = o8;
        }
    };

    // ---- compute phase; PAR = kc (compile-time), ISS: issue next gloads ----
    auto comp = [&](auto parc, auto issc) {
        constexpr int PAR = decltype(parc)::v;
        constexpr int ISS = decltype(issc)::v;
#pragma unroll
        for (int tap = 0; tap < 9; ++tap) {
            const int g = PAR * 9 + tap;
            if (g + 2 < 18) load_af(g + 2);    // depth-2 prefetch
            if constexpr (ISS) {
                if (tap == 3) { issue_gload(1); issue_halo(1); }
            }
            const int kh = tap / 3;
            const int kw = tap - kh * 3;
            const int rowbase = (wid + kh) * XCOLS;
            const int fs = g & 3;
#pragma unroll
            for (int q = 0; q < 4; ++q) {
                const int cc   = q * 16 + nl + kw;          // 0..65
                const int slot = (cc >> 1) & 3;
                bf16x8 bfv = *reinterpret_cast<const bf16x8*>(
                    xs + (rowbase + cc) * 32 + ((kgrp ^ slot) * 8));
#pragma unroll
                for (int mt = 0; mt < 4; ++mt)
                    acc[mt][q] = __builtin_amdgcn_mfma_f32_16x16x32_bf16(
                        af[fs][mt], bfv, acc[mt][q], 0, 0, 0);
            }
        }
    };

    // ---- driver ----
    load_af(0);
    load_af(1);
    issue_gload(0);
    issue_halo(0);
    __syncthreads();          // vmcnt(0) drain: gloads landed in scratch
    cvt();
    __syncthreads();
    comp(IC<0>{}, IC<1>{});   // issues kc=1 gloads+halo after tap 3
    __syncthreads();          // drain kc=1 gloads
    cvt();
    __syncthreads();
    comp(IC<1>{}, IC<0>{});

    // ---- epilogue: D lane layout col=lane&15, row=(lane>>4)*4+reg ----
    const int mrow = kgrp * 4;
    const int h = h0 + wid;
#pragma unroll
    for (int mt = 0; mt < 4; ++mt) {
#pragma unroll
        for (int q = 0; q < 4; ++q) {
            const int ww = w0 + q * 16 + nl;
#pragma unroll
            for (int rg = 0; rg < 4; ++rg) {
                const int co = mt * 16 + mrow + rg;
                out[((size_t)(b * 64 + co) * NH + h) * NW + ww] = acc[mt][q][rg];
            }
        }
    }
}

extern "C" void kernel_launch(void* const* d_in, const int* in_sizes, int n_in,
                              void* d_out, int out_size, void* d_ws, size_t ws_size,
                              hipStream_t stream) {
    const float* x = (const float*)d_in[0];     // [1, 32*64, 256, 256] fp32
    const float* w = (const float*)d_in[1];     // [2048, 64, 3, 3] fp32
    float* out = (float*)d_out;                 // [1, 2048, 256, 256] fp32
    __bf16* pk = (__bf16*)d_ws;                 // 2.25 MB repacked bf16 weights

    {
        int total = NB * 9 * 4 * 2 * 64;        // 147456
        int blk = 256;
        int grid = (total + blk - 1) / blk;     // 576
        hipLaunchKernelGGL(repack_weights_kernel, dim3(grid), dim3(blk), 0, stream,
                           w, pk);
    }
    {
        dim3 grid(8192);                        // 1D, swizzled in-kernel
        hipLaunchKernelGGL(conv_mfma_kernel, grid, dim3(256), 0, stream,
                           x, pk, out);
    }
}